// Round 3
// baseline (442.160 us; speedup 1.0000x reference)
//
#include <hip/hip_runtime.h>
#include <hip/hip_bf16.h>
#include <math.h>

#define B_   16
#define T_   4096
#define KD_  1024
#define AD_  512
#define VD_  1024

typedef float f32x4 __attribute__((ext_vector_type(4)));
typedef short s16x8 __attribute__((ext_vector_type(8)));

static __device__ __forceinline__ short f2bf(float f) {
    __hip_bfloat16 h = __float2bfloat16(f);
    return __builtin_bit_cast(short, h);
}

static __device__ __forceinline__ void gload16(const void* g, void* l) {
    __builtin_amdgcn_global_load_lds(
        (const __attribute__((address_space(1))) void*)(g),
        (__attribute__((address_space(3))) void*)(l), 16, 0, 0);
}

// Blocked GEMM-operand layout: [tile128][kt(=K/32)][chunk c(512)][8 bf16]
//   chunk c = (rowInTile << 2) | ((k & 31) >> 3)   -> LDS offset c*16B, linear.
// A wave's global_load_lds issue (64 lanes x 16B) is 1KB fully contiguous.

// ---------------- kernel 0: key f32 -> bf16, blocked layout ----------------
__global__ __launch_bounds__(256) void cvt_key_blk_kernel(
    const float* __restrict__ key, short* __restrict__ keyB) {
    const size_t nchunk = (size_t)B_ * T_ * KD_ / 8;
    size_t stride = (size_t)gridDim.x * 256;
    for (size_t g = (size_t)blockIdx.x * 256 + threadIdx.x; g < nchunk; g += stride) {
        const float* p = key + g * 8;          // m = g>>7, kc = g&127 -> contiguous
        f32x4 f0 = *reinterpret_cast<const f32x4*>(p);
        f32x4 f1 = *reinterpret_cast<const f32x4*>(p + 4);
        s16x8 h;
        h[0] = f2bf(f0[0]); h[1] = f2bf(f0[1]); h[2] = f2bf(f0[2]); h[3] = f2bf(f0[3]);
        h[4] = f2bf(f1[0]); h[5] = f2bf(f1[1]); h[6] = f2bf(f1[2]); h[7] = f2bf(f1[3]);
        size_t m = g >> 7;
        int kc = (int)(g & 127);
        size_t mt = m >> 7;
        int r = (int)(m & 127);
        int kt = kc >> 2;
        int c = (r << 2) | (kc & 3);
        *reinterpret_cast<s16x8*>(keyB + (((mt * 32 + kt) * 512 + c) << 3)) = h;
    }
}

// ---------------- kernel 1: qb[mat][b][a] = b_bias[a] + query[b,:]·Wq[:,a] ----------------
__global__ __launch_bounds__(256) void qproj_kernel(
    const float* __restrict__ query,
    const float* __restrict__ Wq_mono, const float* __restrict__ b_mono,
    const float* __restrict__ Wq_chunk, const float* __restrict__ b_chunk,
    float* __restrict__ qb) {
    int b = blockIdx.x;       // 0..15
    int mat = blockIdx.y;     // 0..1
    const float* Wq = mat ? Wq_chunk : Wq_mono;
    const float* bb = mat ? b_chunk : b_mono;
    int a0 = threadIdx.x;     // 0..255
    const float* q = query + b * KD_;
    float s0 = 0.f, s1 = 0.f;
    for (int d = 0; d < KD_; ++d) {
        float qv = q[d];
        s0 += qv * Wq[d * AD_ + a0];
        s1 += qv * Wq[d * AD_ + a0 + 256];
    }
    qb[(mat * B_ + b) * AD_ + a0]       = s0 + bb[a0];
    qb[(mat * B_ + b) * AD_ + a0 + 256] = s1 + bb[a0 + 256];
}

// ---------------- kernel 2: weights -> bf16: row-major WkT (fallback) + blocked WkTB ----------------
__global__ __launch_bounds__(256) void wtrans_kernel(
    const float* __restrict__ Wk_mono, const float* __restrict__ Wk_chunk,
    short* __restrict__ WkT, short* __restrict__ WkTB) {
    __shared__ float tile[32][33];
    int n0 = blockIdx.x * 32;    // combined col (0..1023): n<512 mono, else chunk
    int k0 = blockIdx.y * 32;    // row (0..1023)
    int tx = threadIdx.x;        // 0..31
    int ty = threadIdx.y;        // 0..7
    int tid = ty * 32 + tx;
    const float* src;
    int nloc;
    if (n0 < 512) { src = Wk_mono;  nloc = n0; }
    else          { src = Wk_chunk; nloc = n0 - 512; }
#pragma unroll
    for (int i = 0; i < 4; ++i) {
        int k = ty + i * 8;
        tile[k][tx] = src[(size_t)(k0 + k) * AD_ + nloc + tx];   // tile[k_local][n_local]
    }
    __syncthreads();
    // row-major WkT[n][k] (used by fallback GEMM)
#pragma unroll
    for (int i = 0; i < 4; ++i) {
        int r = ty + i * 8;   // local n
        WkT[(size_t)(n0 + r) * KD_ + k0 + tx] = f2bf(tile[tx][r]);
    }
    // blocked WkTB: 128 chunks per 32x32 tile
    if (tid < 128) {
        int r = tid >> 2;       // local n (0..31)
        int sub = tid & 3;      // k-chunk within 32
        s16x8 h;
#pragma unroll
        for (int j = 0; j < 8; ++j)
            h[j] = f2bf(tile[sub * 8 + j][r]);
        int n = n0 + r;
        int nblk = n >> 7;
        int rloc = n & 127;
        int kt = k0 >> 5;
        int c = (rloc << 2) | sub;
        *reinterpret_cast<s16x8*>(WkTB + (((size_t)(nblk * 32 + kt) * 512 + c) << 3)) = h;
    }
}

// ---------------- kernel 3: fused GEMM (blocked bf16 A/B via global_load_lds) + tanh·v -> e_ws ----------------
// m97 structure: 128x128 tile, BK=32, linear LDS, width=16 global_load_lds, 2 barriers/K-step.
// XCD-aware swizzle: all 8 n-tiles of an m-tile land on one XCD -> A L2 reuse.
__global__ __launch_bounds__(256) void gemm_e_bf_kernel(
    const short* __restrict__ keyB,
    const short* __restrict__ WkTB,
    const float* __restrict__ qb,
    const float* __restrict__ v_mono, const float* __restrict__ v_chunk,
    float* __restrict__ e_ws /* [2][B_*T_] */) {
    __shared__ short As[128 * 32];   // linear chunks: c*8 shorts
    __shared__ short Bs[128 * 32];
    int tid = threadIdx.x;
    int bid = blockIdx.x;
    int swz = (bid & 7) * 512 + (bid >> 3);   // XCD-aware (4096 % 8 == 0, bijective)
    int mt = swz >> 3;
    int nt = swz & 7;
    int mBase = mt * 128;
    int nBase = nt * 128;
    int lane = tid & 63;
    int wid = tid >> 6;
    int wr = wid >> 1, wc = wid & 1;
    int col16 = lane & 15, g4 = lane >> 4;

    int c0 = wid * 128 + lane;     // chunk ids this thread stages
    int c1 = c0 + 64;
    const short* pA0 = keyB + (((size_t)mt * 32) * 512 + c0) * 8;
    const short* pA1 = keyB + (((size_t)mt * 32) * 512 + c1) * 8;
    const short* pB0 = WkTB + (((size_t)nt * 32) * 512 + c0) * 8;
    const short* pB1 = WkTB + (((size_t)nt * 32) * 512 + c1) * 8;
    short* sA0 = &As[(wid * 128 + 0) * 8];   // wave-uniform LDS dests
    short* sA1 = &As[(wid * 128 + 64) * 8];
    short* sB0 = &Bs[(wid * 128 + 0) * 8];
    short* sB1 = &Bs[(wid * 128 + 64) * 8];

    f32x4 zero4 = {0.f, 0.f, 0.f, 0.f};
    f32x4 acc[4][4];
#pragma unroll
    for (int m = 0; m < 4; ++m)
#pragma unroll
        for (int n = 0; n < 4; ++n) acc[m][n] = zero4;

    for (int kt = 0; kt < 32; ++kt) {
        gload16(pA0, sA0);
        gload16(pA1, sA1);
        gload16(pB0, sB0);
        gload16(pB1, sB1);
        __syncthreads();
        s16x8 af[4], bfr[4];
#pragma unroll
        for (int m = 0; m < 4; ++m)
            af[m] = *reinterpret_cast<const s16x8*>(&As[(wr * 64 + m * 16 + col16) * 32 + g4 * 8]);
#pragma unroll
        for (int n = 0; n < 4; ++n)
            bfr[n] = *reinterpret_cast<const s16x8*>(&Bs[(wc * 64 + n * 16 + col16) * 32 + g4 * 8]);
#pragma unroll
        for (int m = 0; m < 4; ++m)
#pragma unroll
            for (int n = 0; n < 4; ++n)
                acc[m][n] = __builtin_amdgcn_mfma_f32_16x16x32_bf16(af[m], bfr[n], acc[m][n], 0, 0, 0);
        __syncthreads();
        pA0 += 4096; pA1 += 4096; pB0 += 4096; pB1 += 4096;   // next kt block (512 chunks * 8)
    }

    // epilogue: e[row] += sum_a v[a] * tanh(C[row][a] + qb[b][a])
    int bIdx = mBase >> 12;             // token row / 4096
    int matrix = nBase >> 9;            // 0=mono, 1=chunk
    int aBase = (nBase & 511) + wc * 64 + col16;
    const float* qbRow = qb + (matrix * B_ + bIdx) * AD_;
    const float* vv = matrix ? v_chunk : v_mono;
    float* eArr = e_ws + matrix * (B_ * T_);
    float qcol[4], vcol[4];
#pragma unroll
    for (int n = 0; n < 4; ++n) {
        int a = aBase + n * 16;
        qcol[n] = qbRow[a];
        vcol[n] = vv[a];
    }
#pragma unroll
    for (int m = 0; m < 4; ++m) {
        float s0 = 0.f, s1 = 0.f, s2 = 0.f, s3 = 0.f;
#pragma unroll
        for (int n = 0; n < 4; ++n) {
            s0 += tanhf(acc[m][n][0] + qcol[n]) * vcol[n];
            s1 += tanhf(acc[m][n][1] + qcol[n]) * vcol[n];
            s2 += tanhf(acc[m][n][2] + qcol[n]) * vcol[n];
            s3 += tanhf(acc[m][n][3] + qcol[n]) * vcol[n];
        }
#pragma unroll
        for (int mask = 1; mask < 16; mask <<= 1) {
            s0 += __shfl_xor(s0, mask, 64);
            s1 += __shfl_xor(s1, mask, 64);
            s2 += __shfl_xor(s2, mask, 64);
            s3 += __shfl_xor(s3, mask, 64);
        }
        if (col16 == 0) {
            int rowB = mBase + wr * 64 + m * 16 + g4 * 4;
            atomicAdd(&eArr[rowB + 0], s0);
            atomicAdd(&eArr[rowB + 1], s1);
            atomicAdd(&eArr[rowB + 2], s2);
            atomicAdd(&eArr[rowB + 3], s3);
        }
    }
}

// ---------------- fallback GEMM (f32 A converted in-kernel, row-major WkT) ----------------
__global__ __launch_bounds__(256) void gemm_e_f32a_kernel(
    const float* __restrict__ key,
    const short* __restrict__ WkT,
    const float* __restrict__ qb,
    const float* __restrict__ v_mono, const float* __restrict__ v_chunk,
    float* __restrict__ e_ws) {
    __shared__ short As[128][40];
    __shared__ short Bs[128][40];
    int tid = threadIdx.x;
    int bid = blockIdx.x;
    int mt = bid >> 3;
    int nt = bid & 7;
    int mBase = mt * 128;
    int nBase = nt * 128;
    int lane = tid & 63;
    int wid = tid >> 6;
    int wr = wid >> 1, wc = wid & 1;
    int col16 = lane & 15, g4 = lane >> 4;

    f32x4 zero4 = {0.f, 0.f, 0.f, 0.f};
    f32x4 acc[4][4];
#pragma unroll
    for (int m = 0; m < 4; ++m)
#pragma unroll
        for (int n = 0; n < 4; ++n) acc[m][n] = zero4;

    for (int kt = 0; kt < 32; ++kt) {
        int k0 = kt * 32;
#pragma unroll
        for (int c2 = 0; c2 < 2; ++c2) {
            int c = c2 * 256 + tid;
            int row = c >> 2;
            int kk = (c & 3) * 8;
            const float* srcA = key + (size_t)(mBase + row) * KD_ + k0 + kk;
            f32x4 f0 = *reinterpret_cast<const f32x4*>(srcA);
            f32x4 f1 = *reinterpret_cast<const f32x4*>(srcA + 4);
            s16x8 h;
            h[0] = f2bf(f0[0]); h[1] = f2bf(f0[1]); h[2] = f2bf(f0[2]); h[3] = f2bf(f0[3]);
            h[4] = f2bf(f1[0]); h[5] = f2bf(f1[1]); h[6] = f2bf(f1[2]); h[7] = f2bf(f1[3]);
            *reinterpret_cast<s16x8*>(&As[row][kk]) = h;
            const short* srcB = WkT + (size_t)(nBase + row) * KD_ + k0 + kk;
            *reinterpret_cast<s16x8*>(&Bs[row][kk]) = *reinterpret_cast<const s16x8*>(srcB);
        }
        __syncthreads();
        s16x8 af[4], bfr[4];
#pragma unroll
        for (int m = 0; m < 4; ++m)
            af[m] = *reinterpret_cast<const s16x8*>(&As[wr * 64 + m * 16 + col16][g4 * 8]);
#pragma unroll
        for (int n = 0; n < 4; ++n)
            bfr[n] = *reinterpret_cast<const s16x8*>(&Bs[wc * 64 + n * 16 + col16][g4 * 8]);
#pragma unroll
        for (int m = 0; m < 4; ++m)
#pragma unroll
            for (int n = 0; n < 4; ++n)
                acc[m][n] = __builtin_amdgcn_mfma_f32_16x16x32_bf16(af[m], bfr[n], acc[m][n], 0, 0, 0);
        __syncthreads();
    }

    int bIdx = mBase >> 12;
    int matrix = nBase >> 9;
    int aBase = (nBase & 511) + wc * 64 + col16;
    const float* qbRow = qb + (matrix * B_ + bIdx) * AD_;
    const float* vv = matrix ? v_chunk : v_mono;
    float* eArr = e_ws + matrix * (B_ * T_);
    float qcol[4], vcol[4];
#pragma unroll
    for (int n = 0; n < 4; ++n) {
        int a = aBase + n * 16;
        qcol[n] = qbRow[a];
        vcol[n] = vv[a];
    }
#pragma unroll
    for (int m = 0; m < 4; ++m) {
        float s0 = 0.f, s1 = 0.f, s2 = 0.f, s3 = 0.f;
#pragma unroll
        for (int n = 0; n < 4; ++n) {
            s0 += tanhf(acc[m][n][0] + qcol[n]) * vcol[n];
            s1 += tanhf(acc[m][n][1] + qcol[n]) * vcol[n];
            s2 += tanhf(acc[m][n][2] + qcol[n]) * vcol[n];
            s3 += tanhf(acc[m][n][3] + qcol[n]) * vcol[n];
        }
#pragma unroll
        for (int mask = 1; mask < 16; mask <<= 1) {
            s0 += __shfl_xor(s0, mask, 64);
            s1 += __shfl_xor(s1, mask, 64);
            s2 += __shfl_xor(s2, mask, 64);
            s3 += __shfl_xor(s3, mask, 64);
        }
        if (col16 == 0) {
            int rowB = mBase + wr * 64 + m * 16 + g4 * 4;
            atomicAdd(&eArr[rowB + 0], s0);
            atomicAdd(&eArr[rowB + 1], s1);
            atomicAdd(&eArr[rowB + 2], s2);
            atomicAdd(&eArr[rowB + 3], s3);
        }
    }
}

// ---------------- kernel 4: per-batch scan -> aw, beta ----------------
__global__ __launch_bounds__(256) void scan_kernel(
    const float* __restrict__ e_ws,
    const float* __restrict__ noise,
    const float* __restrict__ r_mono, const float* __restrict__ r_chunk,
    float* __restrict__ aw_out, float* __restrict__ beta_out) {
    __shared__ float s_aw[T_];
    __shared__ float s_sexp[T_];
    __shared__ float s_ad[T_];
    __shared__ float s_w[4];
    int b = blockIdx.x;
    int tid = threadIdx.x;
    int lane = tid & 63;
    int wid4 = tid >> 6;
    int t0 = tid * 16;
    const float* em = e_ws + b * T_;
    const float* ec = e_ws + B_ * T_ + b * T_;
    const float* nz = noise + b * T_;
    float rm = r_mono[0], rc = r_chunk[0];

    float pv[16], lp[16];
    float run = 0.f;
#pragma unroll
    for (int j = 0; j < 16; ++j) {
        float x = em[t0 + j] + rm + nz[t0 + j];
        float p = 1.f / (1.f + expf(-x));
        pv[j] = p;
        float om = fminf(fmaxf(1.f - p, 1e-10f), 1.f);
        lp[j] = run;
        run += logf(om);
    }
    float x = run;
#pragma unroll
    for (int off = 1; off < 64; off <<= 1) {
        float y = __shfl_up(x, off, 64);
        if (lane >= off) x += y;
    }
    if (lane == 63) s_w[wid4] = x;
    __syncthreads();
    float wbase = 0.f;
#pragma unroll
    for (int i = 0; i < 3; ++i) if (i < wid4) wbase += s_w[i];
    float base = 1.f + (wbase + x - run);
#pragma unroll
    for (int j = 0; j < 16; ++j) {
        float aw = pv[j] * expf(base + lp[j]);
        s_aw[t0 + j] = aw;
        aw_out[b * T_ + t0 + j] = aw;
    }
    float evs[16];
    float lmax = -INFINITY;
#pragma unroll
    for (int j = 0; j < 16; ++j) {
        float v = ec[t0 + j] + rc;
        evs[j] = v;
        lmax = fmaxf(lmax, v);
    }
#pragma unroll
    for (int off = 1; off < 64; off <<= 1)
        lmax = fmaxf(lmax, __shfl_xor(lmax, off, 64));
    __syncthreads();
    if (lane == 0) s_w[wid4] = lmax;
    __syncthreads();
    float mx = fmaxf(fmaxf(s_w[0], s_w[1]), fmaxf(s_w[2], s_w[3]));
#pragma unroll
    for (int j = 0; j < 16; ++j)
        s_sexp[t0 + j] = fmaxf(expf(evs[j] - mx), 1e-5f);
    __syncthreads();
#pragma unroll
    for (int j = 0; j < 16; ++j) {
        int t = t0 + j;
        int lo = t - 7; if (lo < 0) lo = 0;
        float d = 0.f;
        for (int i = lo; i <= t; ++i) d += s_sexp[i];
        s_ad[t] = s_aw[t] / d;
    }
    __syncthreads();
#pragma unroll
    for (int j = 0; j < 16; ++j) {
        int t = t0 + j;
        int hi = t + 7; if (hi > T_ - 1) hi = T_ - 1;
        float m2 = 0.f;
        for (int i = t; i <= hi; ++i) m2 += s_ad[i];
        beta_out[b * T_ + t] = s_sexp[t] * m2;
    }
}

// ---------------- kernel 5: cv[b][d] = sum_t beta[b][t]*value[b][t][d] ----------------
__global__ __launch_bounds__(256) void cv_kernel(
    const float* __restrict__ value,
    const float* __restrict__ beta,
    float* __restrict__ cv) {
    __shared__ float s_beta[128];
    int b = blockIdx.x;
    int tc = blockIdx.y;
    int tid = threadIdx.x;
    int t0 = tc * 128;
    if (tid < 128) s_beta[tid] = beta[b * T_ + t0 + tid];
    __syncthreads();
    int d0 = tid * 4;
    f32x4 acc = {0.f, 0.f, 0.f, 0.f};
    const float* vp = value + (size_t)(b * T_ + t0) * VD_ + d0;
#pragma unroll 4
    for (int i = 0; i < 128; ++i) {
        f32x4 v = *reinterpret_cast<const f32x4*>(vp + (size_t)i * VD_);
        float bt = s_beta[i];
        acc[0] += bt * v[0];
        acc[1] += bt * v[1];
        acc[2] += bt * v[2];
        acc[3] += bt * v[3];
    }
    atomicAdd(&cv[b * VD_ + d0 + 0], acc[0]);
    atomicAdd(&cv[b * VD_ + d0 + 1], acc[1]);
    atomicAdd(&cv[b * VD_ + d0 + 2], acc[2]);
    atomicAdd(&cv[b * VD_ + d0 + 3], acc[3]);
}

extern "C" void kernel_launch(void* const* d_in, const int* in_sizes, int n_in,
                              void* d_out, int out_size, void* d_ws, size_t ws_size,
                              hipStream_t stream) {
    const float* key      = (const float*)d_in[0];
    const float* value    = (const float*)d_in[1];
    const float* query    = (const float*)d_in[2];
    const float* noise    = (const float*)d_in[3];
    const float* Wk_mono  = (const float*)d_in[4];
    const float* b_mono   = (const float*)d_in[5];
    const float* Wq_mono  = (const float*)d_in[6];
    const float* Wk_chunk = (const float*)d_in[7];
    const float* b_chunk  = (const float*)d_in[8];
    const float* Wq_chunk = (const float*)d_in[9];
    const float* r_mono   = (const float*)d_in[10];
    const float* r_chunk  = (const float*)d_in[11];
    const float* v_mono   = (const float*)d_in[12];
    const float* v_chunk  = (const float*)d_in[13];
    float* out = (float*)d_out;   // [0,16384): cv ; [16384, 81920): aw

    char* ws = (char*)d_ws;
    size_t off = 0;
    float* e_ws = (float*)(ws + off); off += 2 * B_ * T_ * sizeof(float);      // 512 KB
    float* qb   = (float*)(ws + off); off += 2 * B_ * AD_ * sizeof(float);     // 64 KB
    short* WkT  = (short*)(ws + off); off += (size_t)KD_ * KD_ * 2;            // 2 MB (row-major, fallback)
    short* WkTB = (short*)(ws + off); off += (size_t)KD_ * KD_ * 2;            // 2 MB (blocked)
    float* beta = (float*)(ws + off); off += B_ * T_ * sizeof(float);          // 256 KB
    size_t key_bf_off = off;
    size_t key_bf_bytes = (size_t)B_ * T_ * KD_ * 2;                           // 134 MB
    bool big_ws = (ws_size >= key_bf_off + key_bf_bytes);
    short* keyB = (short*)(ws + key_bf_off);

    hipMemsetAsync(e_ws, 0, 2 * B_ * T_ * sizeof(float), stream);
    hipMemsetAsync(out, 0, B_ * VD_ * sizeof(float), stream);

    qproj_kernel<<<dim3(16, 2), 256, 0, stream>>>(query, Wq_mono, b_mono, Wq_chunk, b_chunk, qb);
    wtrans_kernel<<<dim3(32, 32), dim3(32, 8), 0, stream>>>(Wk_mono, Wk_chunk, WkT, WkTB);
    if (big_ws) {
        cvt_key_blk_kernel<<<4096, 256, 0, stream>>>(key, keyB);
        gemm_e_bf_kernel<<<4096, 256, 0, stream>>>(keyB, WkTB, qb, v_mono, v_chunk, e_ws);
    } else {
        gemm_e_f32a_kernel<<<4096, 256, 0, stream>>>(key, WkT, qb, v_mono, v_chunk, e_ws);
    }
    scan_kernel<<<16, 256, 0, stream>>>(e_ws, noise, r_mono, r_chunk, out + B_ * VD_, beta);
    cv_kernel<<<dim3(16, 32), 256, 0, stream>>>(value, beta, out);
}

// Round 4
// 399.261 us; speedup vs baseline: 1.1074x; 1.1074x over previous
//
#include <hip/hip_runtime.h>
#include <hip/hip_bf16.h>
#include <math.h>

#define B_   16
#define T_   4096
#define KD_  1024
#define AD_  512
#define VD_  1024

typedef float f32x4 __attribute__((ext_vector_type(4)));
typedef short s16x8 __attribute__((ext_vector_type(8)));

static __device__ __forceinline__ short f2bf(float f) {
    __hip_bfloat16 h = __float2bfloat16(f);
    return __builtin_bit_cast(short, h);
}

static __device__ __forceinline__ float fast_tanh(float x) {
    x = fminf(fmaxf(x, -15.f), 15.f);
    float e = __expf(2.f * x);
    return (e - 1.f) / (e + 1.f);
}

static __device__ __forceinline__ void gload16(const void* g, void* l) {
    __builtin_amdgcn_global_load_lds(
        (const __attribute__((address_space(1))) void*)(g),
        (__attribute__((address_space(3))) void*)(l), 16, 0, 0);
}

// Blocked GEMM-operand layout: [tile128][kt(=K/32)][chunk c(512)][8 bf16]
// Bank-swizzled chunk slot: data(row, sub) stored at c = (row<<2) | (sub ^ ((row>>1)&3)).
// LDS stays linear (global_load_lds requirement); read side applies the same XOR.
// ds_read_b128 pattern then spreads 16 rows over 8 distinct 16B slots -> 2-way (free).

// ---------------- kernel 0: key f32 -> bf16, blocked+swizzled layout ----------------
__global__ __launch_bounds__(256) void cvt_key_blk_kernel(
    const float* __restrict__ key, short* __restrict__ keyB) {
    const size_t nchunk = (size_t)B_ * T_ * KD_ / 8;
    size_t stride = (size_t)gridDim.x * 256;
    for (size_t g = (size_t)blockIdx.x * 256 + threadIdx.x; g < nchunk; g += stride) {
        const float* p = key + g * 8;          // m = g>>7, kc = g&127 -> contiguous read
        f32x4 f0 = *reinterpret_cast<const f32x4*>(p);
        f32x4 f1 = *reinterpret_cast<const f32x4*>(p + 4);
        s16x8 h;
        h[0] = f2bf(f0[0]); h[1] = f2bf(f0[1]); h[2] = f2bf(f0[2]); h[3] = f2bf(f0[3]);
        h[4] = f2bf(f1[0]); h[5] = f2bf(f1[1]); h[6] = f2bf(f1[2]); h[7] = f2bf(f1[3]);
        size_t m = g >> 7;
        int kc = (int)(g & 127);
        size_t mt = m >> 7;
        int r = (int)(m & 127);
        int kt = kc >> 2;
        int sub = kc & 3;
        int c = (r << 2) | (sub ^ ((r >> 1) & 3));   // bank swizzle
        *reinterpret_cast<s16x8*>(keyB + (((mt * 32 + kt) * 512 + c) << 3)) = h;
    }
}

// ---------------- kernel 1: qb[mat][b][a] = b_bias[a] + query[b,:]·Wq[:,a] ----------------
__global__ __launch_bounds__(256) void qproj_kernel(
    const float* __restrict__ query,
    const float* __restrict__ Wq_mono, const float* __restrict__ b_mono,
    const float* __restrict__ Wq_chunk, const float* __restrict__ b_chunk,
    float* __restrict__ qb) {
    __shared__ float red[4][64];
    int b = blockIdx.x;       // 0..15
    int mat = blockIdx.y;     // 0..1
    int ac = blockIdx.z;      // 0..7 (64-wide a chunk)
    const float* Wq = mat ? Wq_chunk : Wq_mono;
    const float* bb = mat ? b_chunk : b_mono;
    int al = threadIdx.x & 63;
    int dg = threadIdx.x >> 6;       // 0..3, 256 d's each
    int a = ac * 64 + al;
    const float* q = query + b * KD_ + dg * 256;
    const float* wp = Wq + (size_t)(dg * 256) * AD_ + a;
    float s = 0.f;
#pragma unroll 4
    for (int d = 0; d < 256; ++d)
        s += q[d] * wp[(size_t)d * AD_];
    red[dg][al] = s;
    __syncthreads();
    if (dg == 0) {
        float t = red[0][al] + red[1][al] + red[2][al] + red[3][al];
        qb[(mat * B_ + b) * AD_ + a] = t + bb[a];
    }
}

// ---------------- kernel 2: weights -> bf16: row-major WkT (fallback) + blocked+swizzled WkTB ----------------
__global__ __launch_bounds__(256) void wtrans_kernel(
    const float* __restrict__ Wk_mono, const float* __restrict__ Wk_chunk,
    short* __restrict__ WkT, short* __restrict__ WkTB) {
    __shared__ float tile[32][33];
    int n0 = blockIdx.x * 32;    // combined col (0..1023): n<512 mono, else chunk
    int k0 = blockIdx.y * 32;    // row (0..1023)
    int tx = threadIdx.x;        // 0..31
    int ty = threadIdx.y;        // 0..7
    int tid = ty * 32 + tx;
    const float* src;
    int nloc;
    if (n0 < 512) { src = Wk_mono;  nloc = n0; }
    else          { src = Wk_chunk; nloc = n0 - 512; }
#pragma unroll
    for (int i = 0; i < 4; ++i) {
        int k = ty + i * 8;
        tile[k][tx] = src[(size_t)(k0 + k) * AD_ + nloc + tx];   // tile[k_local][n_local]
    }
    __syncthreads();
#pragma unroll
    for (int i = 0; i < 4; ++i) {
        int r = ty + i * 8;   // local n
        WkT[(size_t)(n0 + r) * KD_ + k0 + tx] = f2bf(tile[tx][r]);
    }
    if (tid < 128) {
        int r = tid >> 2;       // local n (0..31)
        int sub = tid & 3;      // k-chunk within 32
        s16x8 h;
#pragma unroll
        for (int j = 0; j < 8; ++j)
            h[j] = f2bf(tile[sub * 8 + j][r]);
        int n = n0 + r;
        int nblk = n >> 7;
        int rloc = n & 127;
        int kt = k0 >> 5;
        int c = (rloc << 2) | (sub ^ ((rloc >> 1) & 3));   // bank swizzle
        *reinterpret_cast<s16x8*>(WkTB + (((size_t)(nblk * 32 + kt) * 512 + c) << 3)) = h;
    }
}

// ---------------- kernel 3: fused GEMM, 2-phase dbuf + swizzled LDS + tanh·v epilogue ----------------
__global__ __launch_bounds__(256) void gemm_e_bf_kernel(
    const short* __restrict__ keyB,
    const short* __restrict__ WkTB,
    const float* __restrict__ qb,
    const float* __restrict__ v_mono, const float* __restrict__ v_chunk,
    float* __restrict__ e_ws /* [2][B_*T_] */) {
    __shared__ short As[2][128 * 32];   // double-buffered, linear chunk slots
    __shared__ short Bs[2][128 * 32];
    int tid = threadIdx.x;
    int bid = blockIdx.x;
    int swz = (bid & 7) * 512 + (bid >> 3);   // XCD-aware (4096 % 8 == 0, bijective)
    int mt = swz >> 3;
    int nt = swz & 7;
    int mBase = mt * 128;
    int nBase = nt * 128;
    int lane = tid & 63;
    int wid = tid >> 6;
    int wr = wid >> 1, wc = wid & 1;
    int col16 = lane & 15, g4 = lane >> 4;

    int c0 = wid * 128 + lane;     // chunk ids this thread stages
    int c1 = c0 + 64;
    const short* pA0 = keyB + (((size_t)mt * 32) * 512 + c0) * 8;
    const short* pA1 = keyB + (((size_t)mt * 32) * 512 + c1) * 8;
    const short* pB0 = WkTB + (((size_t)nt * 32) * 512 + c0) * 8;
    const short* pB1 = WkTB + (((size_t)nt * 32) * 512 + c1) * 8;
    int sOff0 = (wid * 128 + 0) * 8;   // wave-uniform LDS chunk offsets (shorts)
    int sOff1 = (wid * 128 + 64) * 8;

    // loop-invariant swizzled ds_read offsets (shorts)
    int aoff[4], boff[4];
#pragma unroll
    for (int m = 0; m < 4; ++m) {
        int row = wr * 64 + m * 16 + col16;
        aoff[m] = (row * 4 + (g4 ^ ((row >> 1) & 3))) * 8;
    }
#pragma unroll
    for (int n = 0; n < 4; ++n) {
        int row = wc * 64 + n * 16 + col16;
        boff[n] = (row * 4 + (g4 ^ ((row >> 1) & 3))) * 8;
    }

    f32x4 zero4 = {0.f, 0.f, 0.f, 0.f};
    f32x4 acc[4][4];
#pragma unroll
    for (int m = 0; m < 4; ++m)
#pragma unroll
        for (int n = 0; n < 4; ++n) acc[m][n] = zero4;

    // prologue: stage tile 0 into buf 0
    gload16(pA0, &As[0][sOff0]);
    gload16(pA1, &As[0][sOff1]);
    gload16(pB0, &Bs[0][sOff0]);
    gload16(pB1, &Bs[0][sOff1]);
    pA0 += 4096; pA1 += 4096; pB0 += 4096; pB1 += 4096;
    __syncthreads();

    int cur = 0;
    for (int kt = 0; kt < 31; ++kt) {
        int nxt = cur ^ 1;
        // prefetch next tile (overlaps with MFMA below; drained by the barrier)
        gload16(pA0, &As[nxt][sOff0]);
        gload16(pA1, &As[nxt][sOff1]);
        gload16(pB0, &Bs[nxt][sOff0]);
        gload16(pB1, &Bs[nxt][sOff1]);
        pA0 += 4096; pA1 += 4096; pB0 += 4096; pB1 += 4096;
        // compute current tile
        s16x8 af[4], bfr[4];
#pragma unroll
        for (int m = 0; m < 4; ++m)
            af[m] = *reinterpret_cast<const s16x8*>(&As[cur][aoff[m]]);
#pragma unroll
        for (int n = 0; n < 4; ++n)
            bfr[n] = *reinterpret_cast<const s16x8*>(&Bs[cur][boff[n]]);
#pragma unroll
        for (int m = 0; m < 4; ++m)
#pragma unroll
            for (int n = 0; n < 4; ++n)
                acc[m][n] = __builtin_amdgcn_mfma_f32_16x16x32_bf16(af[m], bfr[n], acc[m][n], 0, 0, 0);
        __syncthreads();   // vmcnt(0)+lgkmcnt(0) drain: next buffer ready, cur free for overwrite
        cur = nxt;
    }
    {   // final tile
        s16x8 af[4], bfr[4];
#pragma unroll
        for (int m = 0; m < 4; ++m)
            af[m] = *reinterpret_cast<const s16x8*>(&As[cur][aoff[m]]);
#pragma unroll
        for (int n = 0; n < 4; ++n)
            bfr[n] = *reinterpret_cast<const s16x8*>(&Bs[cur][boff[n]]);
#pragma unroll
        for (int m = 0; m < 4; ++m)
#pragma unroll
            for (int n = 0; n < 4; ++n)
                acc[m][n] = __builtin_amdgcn_mfma_f32_16x16x32_bf16(af[m], bfr[n], acc[m][n], 0, 0, 0);
    }

    // epilogue: e[row] += sum_a v[a] * tanh(C[row][a] + qb[b][a])
    int bIdx = mBase >> 12;             // token row / 4096
    int matrix = nBase >> 9;            // 0=mono, 1=chunk
    int aBase = (nBase & 511) + wc * 64 + col16;
    const float* qbRow = qb + (matrix * B_ + bIdx) * AD_;
    const float* vv = matrix ? v_chunk : v_mono;
    float* eArr = e_ws + matrix * (B_ * T_);
    float qcol[4], vcol[4];
#pragma unroll
    for (int n = 0; n < 4; ++n) {
        int a = aBase + n * 16;
        qcol[n] = qbRow[a];
        vcol[n] = vv[a];
    }
#pragma unroll
    for (int m = 0; m < 4; ++m) {
        float s0 = 0.f, s1 = 0.f, s2 = 0.f, s3 = 0.f;
#pragma unroll
        for (int n = 0; n < 4; ++n) {
            s0 += fast_tanh(acc[m][n][0] + qcol[n]) * vcol[n];
            s1 += fast_tanh(acc[m][n][1] + qcol[n]) * vcol[n];
            s2 += fast_tanh(acc[m][n][2] + qcol[n]) * vcol[n];
            s3 += fast_tanh(acc[m][n][3] + qcol[n]) * vcol[n];
        }
#pragma unroll
        for (int mask = 1; mask < 16; mask <<= 1) {
            s0 += __shfl_xor(s0, mask, 64);
            s1 += __shfl_xor(s1, mask, 64);
            s2 += __shfl_xor(s2, mask, 64);
            s3 += __shfl_xor(s3, mask, 64);
        }
        if (col16 == 0) {
            int rowB = mBase + wr * 64 + m * 16 + g4 * 4;
            atomicAdd(&eArr[rowB + 0], s0);
            atomicAdd(&eArr[rowB + 1], s1);
            atomicAdd(&eArr[rowB + 2], s2);
            atomicAdd(&eArr[rowB + 3], s3);
        }
    }
}

// ---------------- fallback GEMM (f32 A converted in-kernel, row-major WkT) ----------------
__global__ __launch_bounds__(256) void gemm_e_f32a_kernel(
    const float* __restrict__ key,
    const short* __restrict__ WkT,
    const float* __restrict__ qb,
    const float* __restrict__ v_mono, const float* __restrict__ v_chunk,
    float* __restrict__ e_ws) {
    __shared__ short As[128][40];
    __shared__ short Bs[128][40];
    int tid = threadIdx.x;
    int bid = blockIdx.x;
    int mt = bid >> 3;
    int nt = bid & 7;
    int mBase = mt * 128;
    int nBase = nt * 128;
    int lane = tid & 63;
    int wid = tid >> 6;
    int wr = wid >> 1, wc = wid & 1;
    int col16 = lane & 15, g4 = lane >> 4;

    f32x4 zero4 = {0.f, 0.f, 0.f, 0.f};
    f32x4 acc[4][4];
#pragma unroll
    for (int m = 0; m < 4; ++m)
#pragma unroll
        for (int n = 0; n < 4; ++n) acc[m][n] = zero4;

    for (int kt = 0; kt < 32; ++kt) {
        int k0 = kt * 32;
#pragma unroll
        for (int c2 = 0; c2 < 2; ++c2) {
            int c = c2 * 256 + tid;
            int row = c >> 2;
            int kk = (c & 3) * 8;
            const float* srcA = key + (size_t)(mBase + row) * KD_ + k0 + kk;
            f32x4 f0 = *reinterpret_cast<const f32x4*>(srcA);
            f32x4 f1 = *reinterpret_cast<const f32x4*>(srcA + 4);
            s16x8 h;
            h[0] = f2bf(f0[0]); h[1] = f2bf(f0[1]); h[2] = f2bf(f0[2]); h[3] = f2bf(f0[3]);
            h[4] = f2bf(f1[0]); h[5] = f2bf(f1[1]); h[6] = f2bf(f1[2]); h[7] = f2bf(f1[3]);
            *reinterpret_cast<s16x8*>(&As[row][kk]) = h;
            const short* srcB = WkT + (size_t)(nBase + row) * KD_ + k0 + kk;
            *reinterpret_cast<s16x8*>(&Bs[row][kk]) = *reinterpret_cast<const s16x8*>(srcB);
        }
        __syncthreads();
        s16x8 af[4], bfr[4];
#pragma unroll
        for (int m = 0; m < 4; ++m)
            af[m] = *reinterpret_cast<const s16x8*>(&As[wr * 64 + m * 16 + col16][g4 * 8]);
#pragma unroll
        for (int n = 0; n < 4; ++n)
            bfr[n] = *reinterpret_cast<const s16x8*>(&Bs[wc * 64 + n * 16 + col16][g4 * 8]);
#pragma unroll
        for (int m = 0; m < 4; ++m)
#pragma unroll
            for (int n = 0; n < 4; ++n)
                acc[m][n] = __builtin_amdgcn_mfma_f32_16x16x32_bf16(af[m], bfr[n], acc[m][n], 0, 0, 0);
        __syncthreads();
    }

    int bIdx = mBase >> 12;
    int matrix = nBase >> 9;
    int aBase = (nBase & 511) + wc * 64 + col16;
    const float* qbRow = qb + (matrix * B_ + bIdx) * AD_;
    const float* vv = matrix ? v_chunk : v_mono;
    float* eArr = e_ws + matrix * (B_ * T_);
    float qcol[4], vcol[4];
#pragma unroll
    for (int n = 0; n < 4; ++n) {
        int a = aBase + n * 16;
        qcol[n] = qbRow[a];
        vcol[n] = vv[a];
    }
#pragma unroll
    for (int m = 0; m < 4; ++m) {
        float s0 = 0.f, s1 = 0.f, s2 = 0.f, s3 = 0.f;
#pragma unroll
        for (int n = 0; n < 4; ++n) {
            s0 += fast_tanh(acc[m][n][0] + qcol[n]) * vcol[n];
            s1 += fast_tanh(acc[m][n][1] + qcol[n]) * vcol[n];
            s2 += fast_tanh(acc[m][n][2] + qcol[n]) * vcol[n];
            s3 += fast_tanh(acc[m][n][3] + qcol[n]) * vcol[n];
        }
#pragma unroll
        for (int mask = 1; mask < 16; mask <<= 1) {
            s0 += __shfl_xor(s0, mask, 64);
            s1 += __shfl_xor(s1, mask, 64);
            s2 += __shfl_xor(s2, mask, 64);
            s3 += __shfl_xor(s3, mask, 64);
        }
        if (col16 == 0) {
            int rowB = mBase + wr * 64 + m * 16 + g4 * 4;
            atomicAdd(&eArr[rowB + 0], s0);
            atomicAdd(&eArr[rowB + 1], s1);
            atomicAdd(&eArr[rowB + 2], s2);
            atomicAdd(&eArr[rowB + 3], s3);
        }
    }
}

// ---------------- kernel 4: per-batch scan -> aw, beta ----------------
__global__ __launch_bounds__(256) void scan_kernel(
    const float* __restrict__ e_ws,
    const float* __restrict__ noise,
    const float* __restrict__ r_mono, const float* __restrict__ r_chunk,
    float* __restrict__ aw_out, float* __restrict__ beta_out) {
    __shared__ float s_aw[T_];
    __shared__ float s_sexp[T_];
    __shared__ float s_ad[T_];
    __shared__ float s_w[4];
    int b = blockIdx.x;
    int tid = threadIdx.x;
    int lane = tid & 63;
    int wid4 = tid >> 6;
    int t0 = tid * 16;
    const float* em = e_ws + b * T_;
    const float* ec = e_ws + B_ * T_ + b * T_;
    const float* nz = noise + b * T_;
    float rm = r_mono[0], rc = r_chunk[0];

    float pv[16], lp[16];
    float run = 0.f;
#pragma unroll
    for (int j = 0; j < 16; ++j) {
        float x = em[t0 + j] + rm + nz[t0 + j];
        float p = 1.f / (1.f + expf(-x));
        pv[j] = p;
        float om = fminf(fmaxf(1.f - p, 1e-10f), 1.f);
        lp[j] = run;
        run += logf(om);
    }
    float x = run;
#pragma unroll
    for (int off = 1; off < 64; off <<= 1) {
        float y = __shfl_up(x, off, 64);
        if (lane >= off) x += y;
    }
    if (lane == 63) s_w[wid4] = x;
    __syncthreads();
    float wbase = 0.f;
#pragma unroll
    for (int i = 0; i < 3; ++i) if (i < wid4) wbase += s_w[i];
    float base = 1.f + (wbase + x - run);
#pragma unroll
    for (int j = 0; j < 16; ++j) {
        float aw = pv[j] * expf(base + lp[j]);
        s_aw[t0 + j] = aw;
        aw_out[b * T_ + t0 + j] = aw;
    }
    float evs[16];
    float lmax = -INFINITY;
#pragma unroll
    for (int j = 0; j < 16; ++j) {
        float v = ec[t0 + j] + rc;
        evs[j] = v;
        lmax = fmaxf(lmax, v);
    }
#pragma unroll
    for (int off = 1; off < 64; off <<= 1)
        lmax = fmaxf(lmax, __shfl_xor(lmax, off, 64));
    __syncthreads();
    if (lane == 0) s_w[wid4] = lmax;
    __syncthreads();
    float mx = fmaxf(fmaxf(s_w[0], s_w[1]), fmaxf(s_w[2], s_w[3]));
#pragma unroll
    for (int j = 0; j < 16; ++j)
        s_sexp[t0 + j] = fmaxf(expf(evs[j] - mx), 1e-5f);
    __syncthreads();
#pragma unroll
    for (int j = 0; j < 16; ++j) {
        int t = t0 + j;
        int lo = t - 7; if (lo < 0) lo = 0;
        float d = 0.f;
        for (int i = lo; i <= t; ++i) d += s_sexp[i];
        s_ad[t] = s_aw[t] / d;
    }
    __syncthreads();
#pragma unroll
    for (int j = 0; j < 16; ++j) {
        int t = t0 + j;
        int hi = t + 7; if (hi > T_ - 1) hi = T_ - 1;
        float m2 = 0.f;
        for (int i = t; i <= hi; ++i) m2 += s_ad[i];
        beta_out[b * T_ + t] = s_sexp[t] * m2;
    }
}

// ---------------- kernel 5: cv[b][d] = sum_t beta[b][t]*value[b][t][d] ----------------
__global__ __launch_bounds__(256) void cv_kernel(
    const float* __restrict__ value,
    const float* __restrict__ beta,
    float* __restrict__ cv) {
    __shared__ float s_beta[128];
    int b = blockIdx.x;
    int tc = blockIdx.y;
    int tid = threadIdx.x;
    int t0 = tc * 128;
    if (tid < 128) s_beta[tid] = beta[b * T_ + t0 + tid];
    __syncthreads();
    int d0 = tid * 4;
    f32x4 acc = {0.f, 0.f, 0.f, 0.f};
    const float* vp = value + (size_t)(b * T_ + t0) * VD_ + d0;
#pragma unroll 4
    for (int i = 0; i < 128; ++i) {
        f32x4 v = *reinterpret_cast<const f32x4*>(vp + (size_t)i * VD_);
        float bt = s_beta[i];
        acc[0] += bt * v[0];
        acc[1] += bt * v[1];
        acc[2] += bt * v[2];
        acc[3] += bt * v[3];
    }
    atomicAdd(&cv[b * VD_ + d0 + 0], acc[0]);
    atomicAdd(&cv[b * VD_ + d0 + 1], acc[1]);
    atomicAdd(&cv[b * VD_ + d0 + 2], acc[2]);
    atomicAdd(&cv[b * VD_ + d0 + 3], acc[3]);
}

extern "C" void kernel_launch(void* const* d_in, const int* in_sizes, int n_in,
                              void* d_out, int out_size, void* d_ws, size_t ws_size,
                              hipStream_t stream) {
    const float* key      = (const float*)d_in[0];
    const float* value    = (const float*)d_in[1];
    const float* query    = (const float*)d_in[2];
    const float* noise    = (const float*)d_in[3];
    const float* Wk_mono  = (const float*)d_in[4];
    const float* b_mono   = (const float*)d_in[5];
    const float* Wq_mono  = (const float*)d_in[6];
    const float* Wk_chunk = (const float*)d_in[7];
    const float* b_chunk  = (const float*)d_in[8];
    const float* Wq_chunk = (const float*)d_in[9];
    const float* r_mono   = (const float*)d_in[10];
    const float* r_chunk  = (const float*)d_in[11];
    const float* v_mono   = (const float*)d_in[12];
    const float* v_chunk  = (const float*)d_in[13];
    float* out = (float*)d_out;   // [0,16384): cv ; [16384, 81920): aw

    char* ws = (char*)d_ws;
    size_t off = 0;
    float* e_ws = (float*)(ws + off); off += 2 * B_ * T_ * sizeof(float);      // 512 KB
    float* qb   = (float*)(ws + off); off += 2 * B_ * AD_ * sizeof(float);     // 64 KB
    short* WkT  = (short*)(ws + off); off += (size_t)KD_ * KD_ * 2;            // 2 MB (row-major, fallback)
    short* WkTB = (short*)(ws + off); off += (size_t)KD_ * KD_ * 2;            // 2 MB (blocked+swizzled)
    float* beta = (float*)(ws + off); off += B_ * T_ * sizeof(float);          // 256 KB
    size_t key_bf_off = off;
    size_t key_bf_bytes = (size_t)B_ * T_ * KD_ * 2;                           // 134 MB
    bool big_ws = (ws_size >= key_bf_off + key_bf_bytes);
    short* keyB = (short*)(ws + key_bf_off);

    hipMemsetAsync(e_ws, 0, 2 * B_ * T_ * sizeof(float), stream);
    hipMemsetAsync(out, 0, B_ * VD_ * sizeof(float), stream);

    qproj_kernel<<<dim3(16, 2, 8), 256, 0, stream>>>(query, Wq_mono, b_mono, Wq_chunk, b_chunk, qb);
    wtrans_kernel<<<dim3(32, 32), dim3(32, 8), 0, stream>>>(Wk_mono, Wk_chunk, WkT, WkTB);
    if (big_ws) {
        cvt_key_blk_kernel<<<4096, 256, 0, stream>>>(key, keyB);
        gemm_e_bf_kernel<<<4096, 256, 0, stream>>>(keyB, WkTB, qb, v_mono, v_chunk, e_ws);
    } else {
        gemm_e_f32a_kernel<<<4096, 256, 0, stream>>>(key, WkT, qb, v_mono, v_chunk, e_ws);
    }
    scan_kernel<<<16, 256, 0, stream>>>(e_ws, noise, r_mono, r_chunk, out + B_ * VD_, beta);
    cv_kernel<<<dim3(16, 32), 256, 0, stream>>>(value, beta, out);
}

// Round 5
// 392.589 us; speedup vs baseline: 1.1263x; 1.0170x over previous
//
#include <hip/hip_runtime.h>
#include <hip/hip_bf16.h>
#include <math.h>

#define B_   16
#define T_   4096
#define KD_  1024
#define AD_  512
#define VD_  1024

typedef float f32x4 __attribute__((ext_vector_type(4)));
typedef short s16x8 __attribute__((ext_vector_type(8)));

static __device__ __forceinline__ short f2bf(float f) {
    __hip_bfloat16 h = __float2bfloat16(f);
    return __builtin_bit_cast(short, h);
}

static __device__ __forceinline__ float fast_tanh(float x) {
    x = fminf(fmaxf(x, -15.f), 15.f);
    float e = __expf(2.f * x);
    return (e - 1.f) / (e + 1.f);
}

static __device__ __forceinline__ void gload16(const void* g, void* l) {
    __builtin_amdgcn_global_load_lds(
        (const __attribute__((address_space(1))) void*)(g),
        (__attribute__((address_space(3))) void*)(l), 16, 0, 0);
}

// LDS tile layout (both A and B): 512 chunk-slots of 16B per K-step tile.
// data(row, sub) lives at slot c = (row<<2) | (sub ^ ((row>>1)&3))  [bank swizzle]
// Read side: 16-lane groups hit 8 distinct slots -> 2-way (free).
// B is pre-baked in this layout in global (WkTB) so global_load_lds stays linear.
// A is reg-staged from f32 key (cvt in-kernel) with the same slot XOR on ds_write.

// ---------------- kernel 1: qb[mat][b][a] = b_bias[a] + query[b,:]·Wq[:,a] ----------------
__global__ __launch_bounds__(256) void qproj_kernel(
    const float* __restrict__ query,
    const float* __restrict__ Wq_mono, const float* __restrict__ b_mono,
    const float* __restrict__ Wq_chunk, const float* __restrict__ b_chunk,
    float* __restrict__ qb) {
    __shared__ float red[4][64];
    int b = blockIdx.x;       // 0..15
    int mat = blockIdx.y;     // 0..1
    int ac = blockIdx.z;      // 0..7 (64-wide a chunk)
    const float* Wq = mat ? Wq_chunk : Wq_mono;
    const float* bb = mat ? b_chunk : b_mono;
    int al = threadIdx.x & 63;
    int dg = threadIdx.x >> 6;       // 0..3, 256 d's each
    int a = ac * 64 + al;
    const float* q = query + b * KD_ + dg * 256;
    const float* wp = Wq + (size_t)(dg * 256) * AD_ + a;
    float s = 0.f;
#pragma unroll 4
    for (int d = 0; d < 256; ++d)
        s += q[d] * wp[(size_t)d * AD_];
    red[dg][al] = s;
    __syncthreads();
    if (dg == 0) {
        float t = red[0][al] + red[1][al] + red[2][al] + red[3][al];
        qb[(mat * B_ + b) * AD_ + a] = t + bb[a];
    }
}

// ---------------- kernel 2: weights -> bf16 blocked+swizzled WkTB ----------------
__global__ __launch_bounds__(256) void wtrans_kernel(
    const float* __restrict__ Wk_mono, const float* __restrict__ Wk_chunk,
    short* __restrict__ WkTB) {
    __shared__ float tile[32][33];
    int n0 = blockIdx.x * 32;    // combined col (0..1023): n<512 mono, else chunk
    int k0 = blockIdx.y * 32;    // row (0..1023)
    int tx = threadIdx.x;        // 0..31
    int ty = threadIdx.y;        // 0..7
    int tid = ty * 32 + tx;
    const float* src;
    int nloc;
    if (n0 < 512) { src = Wk_mono;  nloc = n0; }
    else          { src = Wk_chunk; nloc = n0 - 512; }
#pragma unroll
    for (int i = 0; i < 4; ++i) {
        int k = ty + i * 8;
        tile[k][tx] = src[(size_t)(k0 + k) * AD_ + nloc + tx];   // tile[k_local][n_local]
    }
    __syncthreads();
    if (tid < 128) {
        int r = tid >> 2;       // local n (0..31)
        int sub = tid & 3;      // k-chunk within 32
        s16x8 h;
#pragma unroll
        for (int j = 0; j < 8; ++j)
            h[j] = f2bf(tile[sub * 8 + j][r]);
        int n = n0 + r;
        int nblk = n >> 7;
        int rloc = n & 127;
        int kt = k0 >> 5;
        int c = (rloc << 2) | (sub ^ ((rloc >> 1) & 3));   // bank swizzle
        *reinterpret_cast<s16x8*>(WkTB + (((size_t)(nblk * 32 + kt) * 512 + c) << 3)) = h;
    }
}

// ---------------- kernel 3: fused GEMM: f32 A reg-staged (T14) + B gload_lds, tanh·v epilogue ----------------
__global__ __launch_bounds__(256) void gemm_e_kernel(
    const float* __restrict__ key,
    const short* __restrict__ WkTB,
    const float* __restrict__ qb,
    const float* __restrict__ v_mono, const float* __restrict__ v_chunk,
    float* __restrict__ e_ws /* [2][B_*T_] */) {
    __shared__ short As[2][128 * 32];   // double-buffered, swizzled chunk slots
    __shared__ short Bs[2][128 * 32];
    int tid = threadIdx.x;
    int bid = blockIdx.x;
    int swz = (bid & 7) * 512 + (bid >> 3);   // XCD-aware (4096 % 8 == 0, bijective)
    int mt = swz >> 3;
    int nt = swz & 7;
    int mBase = mt * 128;
    int nBase = nt * 128;
    int lane = tid & 63;
    int wid = tid >> 6;
    int wr = wid >> 1, wc = wid & 1;
    int col16 = lane & 15, g4 = lane >> 4;

    // --- B staging (blocked+swizzled global, linear LDS dest) ---
    int c0 = wid * 128 + lane;
    int c1 = c0 + 64;
    const short* pB0 = WkTB + (((size_t)nt * 32) * 512 + c0) * 8;
    const short* pB1 = WkTB + (((size_t)nt * 32) * 512 + c1) * 8;
    int sOff0 = (wid * 128 + 0) * 8;
    int sOff1 = (wid * 128 + 64) * 8;

    // --- A reg-staging: thread t handles row = t>>1, data-subs {d0, d0+1} ---
    int arow = tid >> 1;
    int ad0 = (tid & 1) * 2;
    const float* pA = key + (size_t)(mBase + arow) * KD_ + ad0 * 8;   // += 32 per K-step
    int aswz = (arow >> 1) & 3;
    int aslot0 = (arow * 4 + (ad0 ^ aswz)) * 8;         // LDS short-offsets
    int aslot1 = (arow * 4 + ((ad0 + 1) ^ aswz)) * 8;

    // loop-invariant swizzled ds_read offsets (shorts)
    int aoff[4], boff[4];
#pragma unroll
    for (int m = 0; m < 4; ++m) {
        int row = wr * 64 + m * 16 + col16;
        aoff[m] = (row * 4 + (g4 ^ ((row >> 1) & 3))) * 8;
    }
#pragma unroll
    for (int n = 0; n < 4; ++n) {
        int row = wc * 64 + n * 16 + col16;
        boff[n] = (row * 4 + (g4 ^ ((row >> 1) & 3))) * 8;
    }

    f32x4 zero4 = {0.f, 0.f, 0.f, 0.f};
    f32x4 acc[4][4];
#pragma unroll
    for (int m = 0; m < 4; ++m)
#pragma unroll
        for (int n = 0; n < 4; ++n) acc[m][n] = zero4;

    // ---- prologue: stage tile 0 into buf 0 ----
    gload16(pB0, &Bs[0][sOff0]);
    gload16(pB1, &Bs[0][sOff1]);
    pB0 += 4096; pB1 += 4096;
    {
        f32x4 q0 = *reinterpret_cast<const f32x4*>(pA);
        f32x4 q1 = *reinterpret_cast<const f32x4*>(pA + 4);
        f32x4 q2 = *reinterpret_cast<const f32x4*>(pA + 8);
        f32x4 q3 = *reinterpret_cast<const f32x4*>(pA + 12);
        s16x8 h0, h1;
        h0[0]=f2bf(q0[0]); h0[1]=f2bf(q0[1]); h0[2]=f2bf(q0[2]); h0[3]=f2bf(q0[3]);
        h0[4]=f2bf(q1[0]); h0[5]=f2bf(q1[1]); h0[6]=f2bf(q1[2]); h0[7]=f2bf(q1[3]);
        h1[0]=f2bf(q2[0]); h1[1]=f2bf(q2[1]); h1[2]=f2bf(q2[2]); h1[3]=f2bf(q2[3]);
        h1[4]=f2bf(q3[0]); h1[5]=f2bf(q3[1]); h1[6]=f2bf(q3[2]); h1[7]=f2bf(q3[3]);
        *reinterpret_cast<s16x8*>(&As[0][aslot0]) = h0;
        *reinterpret_cast<s16x8*>(&As[0][aslot1]) = h1;
    }
    const float* pAn = pA + 32;
    __syncthreads();

    int cur = 0;
    for (int kt = 0; kt < 31; ++kt) {
        int nxt = cur ^ 1;
        // issue next-tile staging: B -> LDS DMA, A -> regs (latency hides under MFMA)
        gload16(pB0, &Bs[nxt][sOff0]);
        gload16(pB1, &Bs[nxt][sOff1]);
        pB0 += 4096; pB1 += 4096;
        f32x4 q0 = *reinterpret_cast<const f32x4*>(pAn);
        f32x4 q1 = *reinterpret_cast<const f32x4*>(pAn + 4);
        f32x4 q2 = *reinterpret_cast<const f32x4*>(pAn + 8);
        f32x4 q3 = *reinterpret_cast<const f32x4*>(pAn + 12);
        pAn += 32;
        // compute current tile
        s16x8 af[4], bfr[4];
#pragma unroll
        for (int m = 0; m < 4; ++m)
            af[m] = *reinterpret_cast<const s16x8*>(&As[cur][aoff[m]]);
#pragma unroll
        for (int n = 0; n < 4; ++n)
            bfr[n] = *reinterpret_cast<const s16x8*>(&Bs[cur][boff[n]]);
#pragma unroll
        for (int m = 0; m < 4; ++m)
#pragma unroll
            for (int n = 0; n < 4; ++n)
                acc[m][n] = __builtin_amdgcn_mfma_f32_16x16x32_bf16(af[m], bfr[n], acc[m][n], 0, 0, 0);
        // finish A staging: cvt + swizzled ds_write into nxt
        s16x8 h0, h1;
        h0[0]=f2bf(q0[0]); h0[1]=f2bf(q0[1]); h0[2]=f2bf(q0[2]); h0[3]=f2bf(q0[3]);
        h0[4]=f2bf(q1[0]); h0[5]=f2bf(q1[1]); h0[6]=f2bf(q1[2]); h0[7]=f2bf(q1[3]);
        h1[0]=f2bf(q2[0]); h1[1]=f2bf(q2[1]); h1[2]=f2bf(q2[2]); h1[3]=f2bf(q2[3]);
        h1[4]=f2bf(q3[0]); h1[5]=f2bf(q3[1]); h1[6]=f2bf(q3[2]); h1[7]=f2bf(q3[3]);
        *reinterpret_cast<s16x8*>(&As[nxt][aslot0]) = h0;
        *reinterpret_cast<s16x8*>(&As[nxt][aslot1]) = h1;
        __syncthreads();   // drains B DMA (vmcnt) + A ds_writes (lgkm); publishes nxt
        cur = nxt;
    }
    {   // final tile
        s16x8 af[4], bfr[4];
#pragma unroll
        for (int m = 0; m < 4; ++m)
            af[m] = *reinterpret_cast<const s16x8*>(&As[cur][aoff[m]]);
#pragma unroll
        for (int n = 0; n < 4; ++n)
            bfr[n] = *reinterpret_cast<const s16x8*>(&Bs[cur][boff[n]]);
#pragma unroll
        for (int m = 0; m < 4; ++m)
#pragma unroll
            for (int n = 0; n < 4; ++n)
                acc[m][n] = __builtin_amdgcn_mfma_f32_16x16x32_bf16(af[m], bfr[n], acc[m][n], 0, 0, 0);
    }

    // epilogue: e[row] += sum_a v[a] * tanh(C[row][a] + qb[b][a])
    int bIdx = mBase >> 12;             // token row / 4096
    int matrix = nBase >> 9;            // 0=mono, 1=chunk
    int aBase = (nBase & 511) + wc * 64 + col16;
    const float* qbRow = qb + (matrix * B_ + bIdx) * AD_;
    const float* vv = matrix ? v_chunk : v_mono;
    float* eArr = e_ws + matrix * (B_ * T_);
    float qcol[4], vcol[4];
#pragma unroll
    for (int n = 0; n < 4; ++n) {
        int a = aBase + n * 16;
        qcol[n] = qbRow[a];
        vcol[n] = vv[a];
    }
#pragma unroll
    for (int m = 0; m < 4; ++m) {
        float s0 = 0.f, s1 = 0.f, s2 = 0.f, s3 = 0.f;
#pragma unroll
        for (int n = 0; n < 4; ++n) {
            s0 += fast_tanh(acc[m][n][0] + qcol[n]) * vcol[n];
            s1 += fast_tanh(acc[m][n][1] + qcol[n]) * vcol[n];
            s2 += fast_tanh(acc[m][n][2] + qcol[n]) * vcol[n];
            s3 += fast_tanh(acc[m][n][3] + qcol[n]) * vcol[n];
        }
#pragma unroll
        for (int mask = 1; mask < 16; mask <<= 1) {
            s0 += __shfl_xor(s0, mask, 64);
            s1 += __shfl_xor(s1, mask, 64);
            s2 += __shfl_xor(s2, mask, 64);
            s3 += __shfl_xor(s3, mask, 64);
        }
        if (col16 == 0) {
            int rowB = mBase + wr * 64 + m * 16 + g4 * 4;
            atomicAdd(&eArr[rowB + 0], s0);
            atomicAdd(&eArr[rowB + 1], s1);
            atomicAdd(&eArr[rowB + 2], s2);
            atomicAdd(&eArr[rowB + 3], s3);
        }
    }
}

// ---------------- kernel 4: per-batch scan -> aw, beta ----------------
__global__ __launch_bounds__(256) void scan_kernel(
    const float* __restrict__ e_ws,
    const float* __restrict__ noise,
    const float* __restrict__ r_mono, const float* __restrict__ r_chunk,
    float* __restrict__ aw_out, float* __restrict__ beta_out) {
    __shared__ float s_aw[T_];
    __shared__ float s_sexp[T_];
    __shared__ float s_ad[T_];
    __shared__ float s_w[4];
    int b = blockIdx.x;
    int tid = threadIdx.x;
    int lane = tid & 63;
    int wid4 = tid >> 6;
    int t0 = tid * 16;
    const float* em = e_ws + b * T_;
    const float* ec = e_ws + B_ * T_ + b * T_;
    const float* nz = noise + b * T_;
    float rm = r_mono[0], rc = r_chunk[0];

    float pv[16], lp[16];
    float run = 0.f;
#pragma unroll
    for (int j = 0; j < 16; ++j) {
        float x = em[t0 + j] + rm + nz[t0 + j];
        float p = 1.f / (1.f + expf(-x));
        pv[j] = p;
        float om = fminf(fmaxf(1.f - p, 1e-10f), 1.f);
        lp[j] = run;
        run += logf(om);
    }
    float x = run;
#pragma unroll
    for (int off = 1; off < 64; off <<= 1) {
        float y = __shfl_up(x, off, 64);
        if (lane >= off) x += y;
    }
    if (lane == 63) s_w[wid4] = x;
    __syncthreads();
    float wbase = 0.f;
#pragma unroll
    for (int i = 0; i < 3; ++i) if (i < wid4) wbase += s_w[i];
    float base = 1.f + (wbase + x - run);
#pragma unroll
    for (int j = 0; j < 16; ++j) {
        float aw = pv[j] * expf(base + lp[j]);
        s_aw[t0 + j] = aw;
        aw_out[b * T_ + t0 + j] = aw;
    }
    float evs[16];
    float lmax = -INFINITY;
#pragma unroll
    for (int j = 0; j < 16; ++j) {
        float v = ec[t0 + j] + rc;
        evs[j] = v;
        lmax = fmaxf(lmax, v);
    }
#pragma unroll
    for (int off = 1; off < 64; off <<= 1)
        lmax = fmaxf(lmax, __shfl_xor(lmax, off, 64));
    __syncthreads();
    if (lane == 0) s_w[wid4] = lmax;
    __syncthreads();
    float mx = fmaxf(fmaxf(s_w[0], s_w[1]), fmaxf(s_w[2], s_w[3]));
#pragma unroll
    for (int j = 0; j < 16; ++j)
        s_sexp[t0 + j] = fmaxf(expf(evs[j] - mx), 1e-5f);
    __syncthreads();
#pragma unroll
    for (int j = 0; j < 16; ++j) {
        int t = t0 + j;
        int lo = t - 7; if (lo < 0) lo = 0;
        float d = 0.f;
        for (int i = lo; i <= t; ++i) d += s_sexp[i];
        s_ad[t] = s_aw[t] / d;
    }
    __syncthreads();
#pragma unroll
    for (int j = 0; j < 16; ++j) {
        int t = t0 + j;
        int hi = t + 7; if (hi > T_ - 1) hi = T_ - 1;
        float m2 = 0.f;
        for (int i = t; i <= hi; ++i) m2 += s_ad[i];
        beta_out[b * T_ + t] = s_sexp[t] * m2;
    }
}

// ---------------- kernel 5: cv[b][d] = sum_t beta[b][t]*value[b][t][d] ----------------
__global__ __launch_bounds__(256) void cv_kernel(
    const float* __restrict__ value,
    const float* __restrict__ beta,
    float* __restrict__ cv) {
    __shared__ float s_beta[128];
    int b = blockIdx.x;
    int tc = blockIdx.y;
    int tid = threadIdx.x;
    int t0 = tc * 128;
    if (tid < 128) s_beta[tid] = beta[b * T_ + t0 + tid];
    __syncthreads();
    int d0 = tid * 4;
    f32x4 acc = {0.f, 0.f, 0.f, 0.f};
    const float* vp = value + (size_t)(b * T_ + t0) * VD_ + d0;
#pragma unroll 4
    for (int i = 0; i < 128; ++i) {
        f32x4 v = *reinterpret_cast<const f32x4*>(vp + (size_t)i * VD_);
        float bt = s_beta[i];
        acc[0] += bt * v[0];
        acc[1] += bt * v[1];
        acc[2] += bt * v[2];
        acc[3] += bt * v[3];
    }
    atomicAdd(&cv[b * VD_ + d0 + 0], acc[0]);
    atomicAdd(&cv[b * VD_ + d0 + 1], acc[1]);
    atomicAdd(&cv[b * VD_ + d0 + 2], acc[2]);
    atomicAdd(&cv[b * VD_ + d0 + 3], acc[3]);
}

extern "C" void kernel_launch(void* const* d_in, const int* in_sizes, int n_in,
                              void* d_out, int out_size, void* d_ws, size_t ws_size,
                              hipStream_t stream) {
    const float* key      = (const float*)d_in[0];
    const float* value    = (const float*)d_in[1];
    const float* query    = (const float*)d_in[2];
    const float* noise    = (const float*)d_in[3];
    const float* Wk_mono  = (const float*)d_in[4];
    const float* b_mono   = (const float*)d_in[5];
    const float* Wq_mono  = (const float*)d_in[6];
    const float* Wk_chunk = (const float*)d_in[7];
    const float* b_chunk  = (const float*)d_in[8];
    const float* Wq_chunk = (const float*)d_in[9];
    const float* r_mono   = (const float*)d_in[10];
    const float* r_chunk  = (const float*)d_in[11];
    const float* v_mono   = (const float*)d_in[12];
    const float* v_chunk  = (const float*)d_in[13];
    float* out = (float*)d_out;   // [0,16384): cv ; [16384, 81920): aw

    char* ws = (char*)d_ws;
    size_t off = 0;
    float* e_ws = (float*)(ws + off); off += 2 * B_ * T_ * sizeof(float);      // 512 KB
    float* qb   = (float*)(ws + off); off += 2 * B_ * AD_ * sizeof(float);     // 64 KB
    short* WkTB = (short*)(ws + off); off += (size_t)KD_ * KD_ * 2;            // 2 MB (blocked+swizzled)
    float* beta = (float*)(ws + off); off += B_ * T_ * sizeof(float);          // 256 KB

    hipMemsetAsync(e_ws, 0, 2 * B_ * T_ * sizeof(float), stream);
    hipMemsetAsync(out, 0, B_ * VD_ * sizeof(float), stream);

    qproj_kernel<<<dim3(16, 2, 8), 256, 0, stream>>>(query, Wq_mono, b_mono, Wq_chunk, b_chunk, qb);
    wtrans_kernel<<<dim3(32, 32), dim3(32, 8), 0, stream>>>(Wk_mono, Wk_chunk, WkTB);
    gemm_e_kernel<<<4096, 256, 0, stream>>>(key, WkTB, qb, v_mono, v_chunk, e_ws);
    scan_kernel<<<16, 256, 0, stream>>>(e_ws, noise, r_mono, r_chunk, out + B_ * VD_, beta);
    cv_kernel<<<dim3(16, 32), 256, 0, stream>>>(value, beta, out);
}

// Round 6
// 370.421 us; speedup vs baseline: 1.1937x; 1.0598x over previous
//
#include <hip/hip_runtime.h>
#include <hip/hip_bf16.h>
#include <math.h>

#define B_   16
#define T_   4096
#define KD_  1024
#define AD_  512
#define VD_  1024

typedef float f32x4 __attribute__((ext_vector_type(4)));
typedef short s16x8 __attribute__((ext_vector_type(8)));

static __device__ __forceinline__ short f2bf(float f) {
    __hip_bfloat16 h = __float2bfloat16(f);
    return __builtin_bit_cast(short, h);
}

static __device__ __forceinline__ float fast_tanh(float x) {
    x = fminf(fmaxf(x, -15.f), 15.f);
    float e = __expf(2.f * x);
    return (e - 1.f) / (e + 1.f);
}

static __device__ __forceinline__ void gload16(const void* g, void* l) {
    __builtin_amdgcn_global_load_lds(
        (const __attribute__((address_space(1))) void*)(g),
        (__attribute__((address_space(3))) void*)(l), 16, 0, 0);
}

// Blocked operand layouts (16B chunks, bank-swizzled slots):
//   A (keyB): [mtile256][kt(K/32)][chunk c(1024)][8 bf16], c = (r<<2)|(sub^((r>>1)&3)), r=0..255
//   B (WkTB): [ntile128][kt(K/32)][chunk c(512)][8 bf16],  c = (r<<2)|(sub^((r>>1)&3)), r=0..127
// LDS stays linear (global_load_lds); ds_read applies the same XOR -> 2-way (free).

// ---------------- kernel 0: key f32 -> bf16, blocked+swizzled (256-row tiles) ----------------
__global__ __launch_bounds__(256) void cvt_key_blk_kernel(
    const float* __restrict__ key, short* __restrict__ keyB) {
    const size_t nchunk = (size_t)B_ * T_ * KD_ / 8;
    size_t stride = (size_t)gridDim.x * 256;
    for (size_t g = (size_t)blockIdx.x * 256 + threadIdx.x; g < nchunk; g += stride) {
        const float* p = key + g * 8;          // contiguous read
        f32x4 f0 = *reinterpret_cast<const f32x4*>(p);
        f32x4 f1 = *reinterpret_cast<const f32x4*>(p + 4);
        s16x8 h;
        h[0] = f2bf(f0[0]); h[1] = f2bf(f0[1]); h[2] = f2bf(f0[2]); h[3] = f2bf(f0[3]);
        h[4] = f2bf(f1[0]); h[5] = f2bf(f1[1]); h[6] = f2bf(f1[2]); h[7] = f2bf(f1[3]);
        size_t m = g >> 7;
        int kc = (int)(g & 127);
        size_t mt = m >> 8;                    // 256-row tiles
        int r = (int)(m & 255);
        int kt = kc >> 2;
        int sub = kc & 3;
        int c = (r << 2) | (sub ^ ((r >> 1) & 3));   // bank swizzle
        *reinterpret_cast<s16x8*>(keyB + (((mt * 32 + kt) * 1024 + c) << 3)) = h;
    }
}

// ---------------- kernel 1: qb[mat][b][a] = b_bias[a] + query[b,:]·Wq[:,a] ----------------
__global__ __launch_bounds__(256) void qproj_kernel(
    const float* __restrict__ query,
    const float* __restrict__ Wq_mono, const float* __restrict__ b_mono,
    const float* __restrict__ Wq_chunk, const float* __restrict__ b_chunk,
    float* __restrict__ qb) {
    __shared__ float red[4][64];
    int b = blockIdx.x;       // 0..15
    int mat = blockIdx.y;     // 0..1
    int ac = blockIdx.z;      // 0..7 (64-wide a chunk)
    const float* Wq = mat ? Wq_chunk : Wq_mono;
    const float* bb = mat ? b_chunk : b_mono;
    int al = threadIdx.x & 63;
    int dg = threadIdx.x >> 6;       // 0..3, 256 d's each
    int a = ac * 64 + al;
    const float* q = query + b * KD_ + dg * 256;
    const float* wp = Wq + (size_t)(dg * 256) * AD_ + a;
    float s = 0.f;
#pragma unroll 4
    for (int d = 0; d < 256; ++d)
        s += q[d] * wp[(size_t)d * AD_];
    red[dg][al] = s;
    __syncthreads();
    if (dg == 0) {
        float t = red[0][al] + red[1][al] + red[2][al] + red[3][al];
        qb[(mat * B_ + b) * AD_ + a] = t + bb[a];
    }
}

// ---------------- kernel 2: weights -> bf16 blocked+swizzled WkTB ----------------
__global__ __launch_bounds__(256) void wtrans_kernel(
    const float* __restrict__ Wk_mono, const float* __restrict__ Wk_chunk,
    short* __restrict__ WkTB) {
    __shared__ float tile[32][33];
    int n0 = blockIdx.x * 32;    // combined col (0..1023): n<512 mono, else chunk
    int k0 = blockIdx.y * 32;    // row (0..1023)
    int tx = threadIdx.x;        // 0..31
    int ty = threadIdx.y;        // 0..7
    int tid = ty * 32 + tx;
    const float* src;
    int nloc;
    if (n0 < 512) { src = Wk_mono;  nloc = n0; }
    else          { src = Wk_chunk; nloc = n0 - 512; }
#pragma unroll
    for (int i = 0; i < 4; ++i) {
        int k = ty + i * 8;
        tile[k][tx] = src[(size_t)(k0 + k) * AD_ + nloc + tx];   // tile[k_local][n_local]
    }
    __syncthreads();
    if (tid < 128) {
        int r = tid >> 2;       // local n (0..31)
        int sub = tid & 3;      // k-chunk within 32
        s16x8 h;
#pragma unroll
        for (int j = 0; j < 8; ++j)
            h[j] = f2bf(tile[sub * 8 + j][r]);
        int n = n0 + r;
        int nblk = n >> 7;
        int rloc = n & 127;
        int kt = k0 >> 5;
        int c = (rloc << 2) | (sub ^ ((rloc >> 1) & 3));   // bank swizzle
        *reinterpret_cast<s16x8*>(WkTB + (((size_t)(nblk * 32 + kt) * 512 + c) << 3)) = h;
    }
}

// ---------------- kernel 3: fused GEMM 256x128 tile, 512 thr, 1-barrier dbuf DMA staging ----------------
__global__ __launch_bounds__(512) void gemm_e_kernel(
    const short* __restrict__ keyB,
    const short* __restrict__ WkTB,
    const float* __restrict__ qb,
    const float* __restrict__ v_mono, const float* __restrict__ v_chunk,
    float* __restrict__ e_ws /* [2][B_*T_] */) {
    __shared__ short As[2][256 * 32];   // 32 KB: double-buffered swizzled chunk slots
    __shared__ short Bs[2][128 * 32];   // 16 KB
    int tid = threadIdx.x;
    int bid = blockIdx.x;
    int swz = (bid & 7) * 256 + (bid >> 3);   // XCD-aware (2048 % 8 == 0, bijective)
    int mt = swz >> 3;                        // 0..255
    int nt = swz & 7;                         // 0..7
    int mBase = mt * 256;
    int nBase = nt * 128;
    int lane = tid & 63;
    int wid = tid >> 6;                       // 0..7
    int wr = wid >> 1, wc = wid & 1;          // 4M x 2N waves, 64x64 each
    int col16 = lane & 15, g4 = lane >> 4;

    // staging chunk assignment (wave-contiguous for linear LDS dest)
    int cA0 = wid * 64 + lane;        // A chunks 0..511
    int cA1 = cA0 + 512;              // A chunks 512..1023
    int cB  = wid * 64 + lane;        // B chunks 0..511
    const short* pA0 = keyB + ((size_t)mt * 32 * 1024 + cA0) * 8;
    const short* pA1 = keyB + ((size_t)mt * 32 * 1024 + cA1) * 8;
    const short* pB  = WkTB + ((size_t)nt * 32 * 512 + cB) * 8;
    int sA0 = (wid * 64) * 8;         // LDS short-offsets (wave-uniform)
    int sA1 = (512 + wid * 64) * 8;
    int sB  = (wid * 64) * 8;

    // loop-invariant swizzled ds_read offsets (shorts)
    int aoff[4], boff[4];
#pragma unroll
    for (int m = 0; m < 4; ++m) {
        int row = wr * 64 + m * 16 + col16;           // 0..255
        aoff[m] = (row * 4 + (g4 ^ ((row >> 1) & 3))) * 8;
    }
#pragma unroll
    for (int n = 0; n < 4; ++n) {
        int row = wc * 64 + n * 16 + col16;           // 0..127
        boff[n] = (row * 4 + (g4 ^ ((row >> 1) & 3))) * 8;
    }

    f32x4 zero4 = {0.f, 0.f, 0.f, 0.f};
    f32x4 acc[4][4];
#pragma unroll
    for (int m = 0; m < 4; ++m)
#pragma unroll
        for (int n = 0; n < 4; ++n) acc[m][n] = zero4;

    // prologue: stage tile 0 into buf 0
    gload16(pA0, &As[0][sA0]);
    gload16(pA1, &As[0][sA1]);
    gload16(pB,  &Bs[0][sB]);
    pA0 += 8192; pA1 += 8192; pB += 4096;
    __syncthreads();

    int cur = 0;
    for (int kt = 0; kt < 31; ++kt) {
        int nxt = cur ^ 1;
        // prefetch next tile (overlaps with MFMA; drained by the barrier)
        gload16(pA0, &As[nxt][sA0]);
        gload16(pA1, &As[nxt][sA1]);
        gload16(pB,  &Bs[nxt][sB]);
        pA0 += 8192; pA1 += 8192; pB += 4096;
        // compute current tile
        s16x8 af[4], bfr[4];
#pragma unroll
        for (int m = 0; m < 4; ++m)
            af[m] = *reinterpret_cast<const s16x8*>(&As[cur][aoff[m]]);
#pragma unroll
        for (int n = 0; n < 4; ++n)
            bfr[n] = *reinterpret_cast<const s16x8*>(&Bs[cur][boff[n]]);
#pragma unroll
        for (int m = 0; m < 4; ++m)
#pragma unroll
            for (int n = 0; n < 4; ++n)
                acc[m][n] = __builtin_amdgcn_mfma_f32_16x16x32_bf16(af[m], bfr[n], acc[m][n], 0, 0, 0);
        __syncthreads();   // vmcnt drain: next buffer published, cur free
        cur = nxt;
    }
    {   // final tile
        s16x8 af[4], bfr[4];
#pragma unroll
        for (int m = 0; m < 4; ++m)
            af[m] = *reinterpret_cast<const s16x8*>(&As[cur][aoff[m]]);
#pragma unroll
        for (int n = 0; n < 4; ++n)
            bfr[n] = *reinterpret_cast<const s16x8*>(&Bs[cur][boff[n]]);
#pragma unroll
        for (int m = 0; m < 4; ++m)
#pragma unroll
            for (int n = 0; n < 4; ++n)
                acc[m][n] = __builtin_amdgcn_mfma_f32_16x16x32_bf16(af[m], bfr[n], acc[m][n], 0, 0, 0);
    }

    // epilogue: e[row] += sum_a v[a] * tanh(C[row][a] + qb[b][a])
    int bIdx = mBase >> 12;             // token row / 4096 (256 divides 4096)
    int matrix = nBase >> 9;            // 0=mono, 1=chunk
    int aBase = (nBase & 511) + wc * 64 + col16;
    const float* qbRow = qb + (matrix * B_ + bIdx) * AD_;
    const float* vv = matrix ? v_chunk : v_mono;
    float* eArr = e_ws + matrix * (B_ * T_);
    float qcol[4], vcol[4];
#pragma unroll
    for (int n = 0; n < 4; ++n) {
        int a = aBase + n * 16;
        qcol[n] = qbRow[a];
        vcol[n] = vv[a];
    }
#pragma unroll
    for (int m = 0; m < 4; ++m) {
        float s0 = 0.f, s1 = 0.f, s2 = 0.f, s3 = 0.f;
#pragma unroll
        for (int n = 0; n < 4; ++n) {
            s0 += fast_tanh(acc[m][n][0] + qcol[n]) * vcol[n];
            s1 += fast_tanh(acc[m][n][1] + qcol[n]) * vcol[n];
            s2 += fast_tanh(acc[m][n][2] + qcol[n]) * vcol[n];
            s3 += fast_tanh(acc[m][n][3] + qcol[n]) * vcol[n];
        }
#pragma unroll
        for (int mask = 1; mask < 16; mask <<= 1) {
            s0 += __shfl_xor(s0, mask, 64);
            s1 += __shfl_xor(s1, mask, 64);
            s2 += __shfl_xor(s2, mask, 64);
            s3 += __shfl_xor(s3, mask, 64);
        }
        if (col16 == 0) {
            int rowB = mBase + wr * 64 + m * 16 + g4 * 4;
            atomicAdd(&eArr[rowB + 0], s0);
            atomicAdd(&eArr[rowB + 1], s1);
            atomicAdd(&eArr[rowB + 2], s2);
            atomicAdd(&eArr[rowB + 3], s3);
        }
    }
}

// ---------------- kernel 4: per-batch scan -> aw, beta ----------------
__global__ __launch_bounds__(256) void scan_kernel(
    const float* __restrict__ e_ws,
    const float* __restrict__ noise,
    const float* __restrict__ r_mono, const float* __restrict__ r_chunk,
    float* __restrict__ aw_out, float* __restrict__ beta_out) {
    __shared__ float s_aw[T_];
    __shared__ float s_sexp[T_];
    __shared__ float s_ad[T_];
    __shared__ float s_w[4];
    int b = blockIdx.x;
    int tid = threadIdx.x;
    int lane = tid & 63;
    int wid4 = tid >> 6;
    int t0 = tid * 16;
    const float* em = e_ws + b * T_;
    const float* ec = e_ws + B_ * T_ + b * T_;
    const float* nz = noise + b * T_;
    float rm = r_mono[0], rc = r_chunk[0];

    float pv[16], lp[16];
    float run = 0.f;
#pragma unroll
    for (int j = 0; j < 16; ++j) {
        float x = em[t0 + j] + rm + nz[t0 + j];
        float p = 1.f / (1.f + expf(-x));
        pv[j] = p;
        float om = fminf(fmaxf(1.f - p, 1e-10f), 1.f);
        lp[j] = run;
        run += logf(om);
    }
    float x = run;
#pragma unroll
    for (int off = 1; off < 64; off <<= 1) {
        float y = __shfl_up(x, off, 64);
        if (lane >= off) x += y;
    }
    if (lane == 63) s_w[wid4] = x;
    __syncthreads();
    float wbase = 0.f;
#pragma unroll
    for (int i = 0; i < 3; ++i) if (i < wid4) wbase += s_w[i];
    float base = 1.f + (wbase + x - run);
#pragma unroll
    for (int j = 0; j < 16; ++j) {
        float aw = pv[j] * expf(base + lp[j]);
        s_aw[t0 + j] = aw;
        aw_out[b * T_ + t0 + j] = aw;
    }
    float evs[16];
    float lmax = -INFINITY;
#pragma unroll
    for (int j = 0; j < 16; ++j) {
        float v = ec[t0 + j] + rc;
        evs[j] = v;
        lmax = fmaxf(lmax, v);
    }
#pragma unroll
    for (int off = 1; off < 64; off <<= 1)
        lmax = fmaxf(lmax, __shfl_xor(lmax, off, 64));
    __syncthreads();
    if (lane == 0) s_w[wid4] = lmax;
    __syncthreads();
    float mx = fmaxf(fmaxf(s_w[0], s_w[1]), fmaxf(s_w[2], s_w[3]));
#pragma unroll
    for (int j = 0; j < 16; ++j)
        s_sexp[t0 + j] = fmaxf(expf(evs[j] - mx), 1e-5f);
    __syncthreads();
#pragma unroll
    for (int j = 0; j < 16; ++j) {
        int t = t0 + j;
        int lo = t - 7; if (lo < 0) lo = 0;
        float d = 0.f;
        for (int i = lo; i <= t; ++i) d += s_sexp[i];
        s_ad[t] = s_aw[t] / d;
    }
    __syncthreads();
#pragma unroll
    for (int j = 0; j < 16; ++j) {
        int t = t0 + j;
        int hi = t + 7; if (hi > T_ - 1) hi = T_ - 1;
        float m2 = 0.f;
        for (int i = t; i <= hi; ++i) m2 += s_ad[i];
        beta_out[b * T_ + t] = s_sexp[t] * m2;
    }
}

// ---------------- kernel 5: cv[b][d] = sum_t beta[b][t]*value[b][t][d] ----------------
__global__ __launch_bounds__(256) void cv_kernel(
    const float* __restrict__ value,
    const float* __restrict__ beta,
    float* __restrict__ cv) {
    __shared__ float s_beta[128];
    int b = blockIdx.x;
    int tc = blockIdx.y;
    int tid = threadIdx.x;
    int t0 = tc * 128;
    if (tid < 128) s_beta[tid] = beta[b * T_ + t0 + tid];
    __syncthreads();
    int d0 = tid * 4;
    f32x4 acc = {0.f, 0.f, 0.f, 0.f};
    const float* vp = value + (size_t)(b * T_ + t0) * VD_ + d0;
#pragma unroll 4
    for (int i = 0; i < 128; ++i) {
        f32x4 v = *reinterpret_cast<const f32x4*>(vp + (size_t)i * VD_);
        float bt = s_beta[i];
        acc[0] += bt * v[0];
        acc[1] += bt * v[1];
        acc[2] += bt * v[2];
        acc[3] += bt * v[3];
    }
    atomicAdd(&cv[b * VD_ + d0 + 0], acc[0]);
    atomicAdd(&cv[b * VD_ + d0 + 1], acc[1]);
    atomicAdd(&cv[b * VD_ + d0 + 2], acc[2]);
    atomicAdd(&cv[b * VD_ + d0 + 3], acc[3]);
}

extern "C" void kernel_launch(void* const* d_in, const int* in_sizes, int n_in,
                              void* d_out, int out_size, void* d_ws, size_t ws_size,
                              hipStream_t stream) {
    const float* key      = (const float*)d_in[0];
    const float* value    = (const float*)d_in[1];
    const float* query    = (const float*)d_in[2];
    const float* noise    = (const float*)d_in[3];
    const float* Wk_mono  = (const float*)d_in[4];
    const float* b_mono   = (const float*)d_in[5];
    const float* Wq_mono  = (const float*)d_in[6];
    const float* Wk_chunk = (const float*)d_in[7];
    const float* b_chunk  = (const float*)d_in[8];
    const float* Wq_chunk = (const float*)d_in[9];
    const float* r_mono   = (const float*)d_in[10];
    const float* r_chunk  = (const float*)d_in[11];
    const float* v_mono   = (const float*)d_in[12];
    const float* v_chunk  = (const float*)d_in[13];
    float* out = (float*)d_out;   // [0,16384): cv ; [16384, 81920): aw

    char* ws = (char*)d_ws;
    size_t off = 0;
    float* e_ws = (float*)(ws + off); off += 2 * B_ * T_ * sizeof(float);      // 512 KB
    float* qb   = (float*)(ws + off); off += 2 * B_ * AD_ * sizeof(float);     // 64 KB
    short* WkTB = (short*)(ws + off); off += (size_t)KD_ * KD_ * 2;            // 2 MB (blocked+swizzled)
    float* beta = (float*)(ws + off); off += B_ * T_ * sizeof(float);          // 256 KB
    short* keyB = (short*)(ws + off);                                          // 134 MB (blocked+swizzled)

    hipMemsetAsync(e_ws, 0, 2 * B_ * T_ * sizeof(float), stream);
    hipMemsetAsync(out, 0, B_ * VD_ * sizeof(float), stream);

    qproj_kernel<<<dim3(16, 2, 8), 256, 0, stream>>>(query, Wq_mono, b_mono, Wq_chunk, b_chunk, qb);
    wtrans_kernel<<<dim3(32, 32), dim3(32, 8), 0, stream>>>(Wk_mono, Wk_chunk, WkTB);
    cvt_key_blk_kernel<<<4096, 256, 0, stream>>>(key, keyB);
    gemm_e_kernel<<<2048, 512, 0, stream>>>(keyB, WkTB, qb, v_mono, v_chunk, e_ws);
    scan_kernel<<<16, 256, 0, stream>>>(e_ws, noise, r_mono, r_chunk, out + B_ * VD_, beta);
    cv_kernel<<<dim3(16, 32), 256, 0, stream>>>(value, beta, out);
}